// Round 22
// baseline (128.888 us; speedup 1.0000x reference)
//
#include <hip/hip_runtime.h>
#include <hip/hip_bf16.h>
#include <math.h>

// KAN 2-layer forward, MI355X (gfx950) — round 22 = r18/r21 + ONE isolated A/B:
// gemm2 staging order features->GLL->sync  ==>  GLL->h-prefetch->features->sync
// (B-load L2 latency now covered by the mandatory feature VALU instead of being
// fully exposed at the vmcnt(0) drain). Everything else byte-identical to r21.
//   init_fused   : prep W1, prep W2, expand x -> F1.
//   kan_gemm1    : 512 thr, 128x128, BK=64, dbuf, counted vmcnt(4), setprio.
//   kan_gemm2    : 512 thr, BM=128, BN=256, BK=64, split-K=8, 48KB LDS,
//                  plain 2-barrier, bf16 partials. 2 blk/CU = 16 waves/CU.
//   reduce_split : sum 8 bf16 slices in f32 -> out.
// Ledger (gemm2): r6 69 | cnt-vmcnt 158 | BK32 87 | BN128 98 | reg-only 212 |
// fence 229 | XCD 71.5 | r13 67 | LDS-Bdbuf 98 | r16 65 | splitK16 69 |
// reg-Bdbuf 93 | 1024thr 79.  gemm1: 256t 48 | 512t 45 | 1024t regress.

typedef __attribute__((ext_vector_type(8))) short bf16x8;   // 8 x bf16
typedef __attribute__((ext_vector_type(4))) float f32x4;
typedef __attribute__((ext_vector_type(4))) unsigned short u16x4;

#define TOKENS 8192
#define D_IN   256
#define D_HID  1024

// ---- exact uniform-cubic-B-spline features (closed form) ----
__device__ __forceinline__ void kan_features(float x, float f[8]) {
    f[0] = x * __builtin_amdgcn_rcpf(1.0f + __expf(-x));   // silu via v_rcp
    const float s = (x + 1.0f) * 1.5f + 3.0f;
    const float cf = floorf(s);
    const float u = s - cf;
    const int c = (int)cf;
    const float u2 = u * u, u3 = u2 * u;
    const float k6 = 1.0f / 6.0f;
    const float v3 = u3 * k6;
    const float v2 = (-3.0f * u3 + 3.0f * u2 + 3.0f * u + 1.0f) * k6;
    const float v1 = (3.0f * u3 - 6.0f * u2 + 4.0f) * k6;
    const float w1 = 1.0f - u;
    const float v0 = w1 * w1 * w1 * k6;
    const bool in = (s >= 0.0f) && (s < 9.0f);
#pragma unroll
    for (int j = 0; j < 6; ++j) {
        int d = c - j;
        float bv = (d == 0) ? v3 : (d == 1) ? v2 : (d == 2) ? v1 : (d == 3) ? v0 : 0.0f;
        f[1 + j] = in ? bv : 0.0f;
    }
    f[7] = 0.0f;
}

__device__ __forceinline__ void features_to_bf16(const float f[8], __hip_bfloat16 fb[8]) {
#pragma unroll
    for (int j = 0; j < 8; ++j) fb[j] = __float2bfloat16(f[j]);
}

// ---------------- fused init: expand_x (blocks 0..8191), prep W1, prep W2 ----------
__global__ void init_fused(const float* __restrict__ X, __hip_bfloat16* __restrict__ F,
                           const float* __restrict__ bw1, const float* __restrict__ sw1,
                           const float* __restrict__ sc1, __hip_bfloat16* __restrict__ W1,
                           const float* __restrict__ bw2, const float* __restrict__ sw2,
                           const float* __restrict__ sc2, __hip_bfloat16* __restrict__ W2) {
    const int b = blockIdx.x;
    if (b < 8192) {                          // expand x: 2M elements
        int idx = b * 256 + threadIdx.x;
        float f[8];
        kan_features(X[idx], f);
        __hip_bfloat16 fb[8];
        features_to_bf16(f, fb);
        *(bf16x8*)&F[(size_t)idx * 8] = *(bf16x8*)fb;
        return;
    }
    const bool w1 = (b < 9216);
    int idx = (w1 ? (b - 8192) : (b - 9216)) * 256 + threadIdx.x;   // < 262144
    const float* bw = w1 ? bw1 : bw2;
    const float* sw = w1 ? sw1 : sw2;
    const float* sc = w1 ? sc1 : sc2;
    __hip_bfloat16* Wo = w1 ? W1 : W2;
    float scl = sc[idx];
    __hip_bfloat16 row[8];
    row[0] = __float2bfloat16(bw[idx]);
#pragma unroll
    for (int j = 0; j < 6; ++j)
        row[1 + j] = __float2bfloat16(sw[idx * 6 + j] * scl);
    row[7] = __float2bfloat16(0.0f);
    *(bf16x8*)&Wo[(size_t)idx * 8] = *(bf16x8*)row;
}

#define GLL(src, dst) __builtin_amdgcn_global_load_lds(                         \
    (const __attribute__((address_space(1))) void*)(src),                       \
    (__attribute__((address_space(3))) void*)(dst), 16, 0, 0)

// ---------------- GEMM1: H = bf16(GELU(F1 @ W1^T)), 128x128, BK=64, 512 thr ----
__global__ __launch_bounds__(512, 2)
void kan_gemm1(const __hip_bfloat16* __restrict__ A,
               const __hip_bfloat16* __restrict__ W,
               __hip_bfloat16* __restrict__ H) {
    constexpr int K = D_IN * 8;            // 2048
    constexpr int NT = K / 64;             // 32 k-tiles
    __shared__ __hip_bfloat16 Al[2][128 * 64];
    __shared__ __hip_bfloat16 Bl[2][128 * 64];

    const int tid = threadIdx.x;
    const int wid = tid >> 6, lane = tid & 63;
    const int wm = wid >> 2, wn = wid & 3;  // 2x4 waves: 64-row x 32-col tiles
    const int lr = lane & 15, lg = lane >> 4;
    const int n0 = blockIdx.x * 128, o0 = blockIdx.y * 128;

    int srow[2], sslot[2];
#pragma unroll
    for (int p = 0; p < 2; ++p) {
        int item = tid + p * 512;
        srow[p] = item >> 3;
        sslot[p] = (item & 7) ^ (srow[p] & 7);
    }
    int aoff[2][4], boff[2][2];
#pragma unroll
    for (int ks = 0; ks < 2; ++ks) {
#pragma unroll
        for (int f = 0; f < 4; ++f) {
            int ar = wm * 64 + f * 16 + lr;
            aoff[ks][f] = ar * 64 + (((ks * 4 + lg) ^ (ar & 7)) * 8);
        }
#pragma unroll
        for (int f = 0; f < 2; ++f) {
            int br = wn * 32 + f * 16 + lr;
            boff[ks][f] = br * 64 + (((ks * 4 + lg) ^ (br & 7)) * 8);
        }
    }

    f32x4 acc[4][2] = {};

#define STG1(buf, kt)                                                           \
    do {                                                                        \
        _Pragma("unroll")                                                       \
        for (int p = 0; p < 2; ++p) {                                           \
            GLL(A + (size_t)(n0 + srow[p]) * K + (kt) * 64 + sslot[p] * 8,      \
                &Al[buf][(tid + p * 512) * 8]);                                 \
            GLL(W + (size_t)(o0 + srow[p]) * K + (kt) * 64 + sslot[p] * 8,      \
                &Bl[buf][(tid + p * 512) * 8]);                                 \
        }                                                                       \
    } while (0)

    STG1(0, 0);
    STG1(1, 1);
    for (int t = 0; t < NT; ++t) {
        const int cur = t & 1;
        asm volatile("s_waitcnt vmcnt(4)" ::: "memory");
        __builtin_amdgcn_s_barrier();
        __builtin_amdgcn_sched_barrier(0);
        __builtin_amdgcn_s_setprio(1);
#pragma unroll
        for (int ks = 0; ks < 2; ++ks) {
            bf16x8 af[4], bfr[2];
#pragma unroll
            for (int f = 0; f < 4; ++f) af[f] = *(const bf16x8*)&Al[cur][aoff[ks][f]];
#pragma unroll
            for (int f = 0; f < 2; ++f) bfr[f] = *(const bf16x8*)&Bl[cur][boff[ks][f]];
#pragma unroll
            for (int fm = 0; fm < 4; ++fm)
#pragma unroll
                for (int fn = 0; fn < 2; ++fn)
                    acc[fm][fn] = __builtin_amdgcn_mfma_f32_16x16x32_bf16(
                        af[fm], bfr[fn], acc[fm][fn], 0, 0, 0);
        }
        __builtin_amdgcn_s_setprio(0);
        asm volatile("s_waitcnt lgkmcnt(0)" ::: "memory");
        __builtin_amdgcn_s_barrier();
        __builtin_amdgcn_sched_barrier(0);
        const int kn = (t + 2 < NT) ? t + 2 : NT - 1;
        STG1(cur, kn);
    }
#undef STG1
#pragma unroll
    for (int fm = 0; fm < 4; ++fm) {
#pragma unroll
        for (int fn = 0; fn < 2; ++fn) {
            int col = o0 + wn * 32 + fn * 16 + lr;
#pragma unroll
            for (int r = 0; r < 4; ++r) {
                int row = n0 + wm * 64 + fm * 16 + lg * 4 + r;
                float v = acc[fm][fn][r];
                float g = 0.5f * v * (1.0f + erff(v * 0.70710678118f));
                H[(size_t)row * D_HID + col] = __float2bfloat16(g);
            }
        }
    }
}

// ---------------- GEMM2: r18 body, staging reordered GLL -> h -> features ----
__global__ __launch_bounds__(512, 2)
void kan_gemm2(const __hip_bfloat16* __restrict__ H,
               const __hip_bfloat16* __restrict__ W,
               __hip_bfloat16* __restrict__ P) {
    constexpr int OUT = D_IN, KD = D_HID * 8;   // 8192
    constexpr int NTT = KD / 64;                // 128 k-tiles
    __shared__ __hip_bfloat16 Al[128 * 64];     // 16KB
    __shared__ __hip_bfloat16 Bl[256 * 64];     // 32KB (reused as f32 in epi)

    const int tid = threadIdx.x;
    const int wid = tid >> 6, lane = tid & 63;
    const int wm = wid >> 2, wn = wid & 3;      // 2x4 waves: 64-row x 64-col tiles
    const int lr = lane & 15, lg = lane >> 4;
    const int n0 = blockIdx.x * 128;

    const int per = NTT / 8;                    // 16
    const int ks0 = blockIdx.z * per, ks1 = ks0 + per;

    int srow[4], sslot[4];
#pragma unroll
    for (int p = 0; p < 4; ++p) {
        int item = tid + p * 512;
        srow[p] = item >> 3;
        sslot[p] = (item & 7) ^ (srow[p] & 7);
    }
    const int ar0 = tid >> 3, ac = tid & 7;
    const __hip_bfloat16* hp0 = H + (size_t)(n0 + ar0) * D_HID + ac;
    const __hip_bfloat16* hp1 = H + (size_t)(n0 + ar0 + 64) * D_HID + ac;
    const int aw0 = ar0 * 64 + ((ac ^ (ar0 & 7)) * 8);
    const int aw1 = (ar0 + 64) * 64 + ((ac ^ (ar0 & 7)) * 8);

    int aoff[2][4], boff[2][4];
#pragma unroll
    for (int ks = 0; ks < 2; ++ks)
#pragma unroll
        for (int f = 0; f < 4; ++f) {
            int ar = wm * 64 + f * 16 + lr;
            int br = wn * 64 + f * 16 + lr;
            aoff[ks][f] = ar * 64 + (((ks * 4 + lg) ^ (ar & 7)) * 8);
            boff[ks][f] = br * 64 + (((ks * 4 + lg) ^ (br & 7)) * 8);
        }

    f32x4 acc[4][4] = {};

    float hv0 = __bfloat162float(hp0[(size_t)ks0 * 8]);
    float hv1 = __bfloat162float(hp1[(size_t)ks0 * 8]);

    for (int kt = ks0; kt < ks1; ++kt) {
        // B loads FIRST: 4 GLL issue here and fly under h-prefetch + feature VALU
#pragma unroll
        for (int p = 0; p < 4; ++p)
            GLL(W + (size_t)srow[p] * KD + (size_t)kt * 64 + sslot[p] * 8,
                &Bl[(tid + p * 512) * 8]);
        float hc0 = hv0, hc1 = hv1;
        const int knext = (kt + 1 < ks1) ? kt + 1 : ks1 - 1;
        hv0 = __bfloat162float(hp0[(size_t)knext * 8]);
        hv1 = __bfloat162float(hp1[(size_t)knext * 8]);
        {   // features -> swizzled LDS (covers the GLL L2 latency)
            float ff[8]; __hip_bfloat16 fb[8];
            kan_features(hc0, ff); features_to_bf16(ff, fb);
            *(bf16x8*)&Al[aw0] = *(bf16x8*)fb;
            kan_features(hc1, ff); features_to_bf16(ff, fb);
            *(bf16x8*)&Al[aw1] = *(bf16x8*)fb;
        }
        __syncthreads();
#pragma unroll
        for (int ks = 0; ks < 2; ++ks) {
            bf16x8 af[4], bfr[4];
#pragma unroll
            for (int f = 0; f < 4; ++f) af[f] = *(const bf16x8*)&Al[aoff[ks][f]];
#pragma unroll
            for (int f = 0; f < 4; ++f) bfr[f] = *(const bf16x8*)&Bl[boff[ks][f]];
#pragma unroll
            for (int fm = 0; fm < 4; ++fm)
#pragma unroll
                for (int fn = 0; fn < 4; ++fn)
                    acc[fm][fn] = __builtin_amdgcn_mfma_f32_16x16x32_bf16(
                        af[fm], bfr[fn], acc[fm][fn], 0, 0, 0);
        }
        __syncthreads();
    }

    // ---- epilogue: 4 quarter-passes (32 rows x 256 cols f32 in Bl), bf16 stores ----
    float* Pl = (float*)Bl;
    const size_t zoff = (size_t)blockIdx.z * TOKENS * OUT;
#pragma unroll
    for (int q = 0; q < 4; ++q) {
        __syncthreads();
        if (wm == (q >> 1)) {
#pragma unroll
            for (int fp = 0; fp < 2; ++fp) {     // fm = (q&1)*2 + fp
                int fm = (q & 1) * 2 + fp;
#pragma unroll
                for (int fn = 0; fn < 4; ++fn) {
                    int c = wn * 64 + fn * 16 + lr;
#pragma unroll
                    for (int r = 0; r < 4; ++r)
                        Pl[(fp * 16 + lg * 4 + r) * 256 + c] = acc[fm][fn][r];
                }
            }
        }
        __syncthreads();
#pragma unroll
        for (int p = 0; p < 4; ++p) {
            int v = tid + p * 512;               // 0..2047
            int row = v >> 6, cv = (v & 63) * 4;
            const float* src = &Pl[row * 256 + cv];
            __hip_bfloat16 ob[4];
#pragma unroll
            for (int j = 0; j < 4; ++j) ob[j] = __float2bfloat16(src[j]);
            *(u16x4*)&P[zoff + (size_t)(n0 + q * 32 + row) * OUT + cv] =
                *(const u16x4*)ob;
        }
    }
}

// ---------------- reduce 8 bf16 partial slices -> f32 out ----------------
__global__ void reduce_split(const __hip_bfloat16* __restrict__ P,
                             float* __restrict__ out, int nvec) {
    int i = blockIdx.x * 256 + threadIdx.x;
    if (i >= nvec) return;                       // i indexes groups of 4 elems
    float s[4] = {0.f, 0.f, 0.f, 0.f};
#pragma unroll
    for (int z = 0; z < 8; ++z) {
        u16x4 v = *(const u16x4*)&P[(size_t)z * TOKENS * D_IN + (size_t)i * 4];
#pragma unroll
        for (int j = 0; j < 4; ++j) {
            unsigned int bits = ((unsigned int)(unsigned short)v[j]) << 16;
            s[j] += __uint_as_float(bits);       // exact bf16 -> f32
        }
    }
    f32x4 o = {s[0], s[1], s[2], s[3]};
    *(f32x4*)&out[(size_t)i * 4] = o;
}

extern "C" void kernel_launch(void* const* d_in, const int* in_sizes, int n_in,
                              void* d_out, int out_size, void* d_ws, size_t ws_size,
                              hipStream_t stream) {
    const float* x   = (const float*)d_in[0];
    const float* bw1 = (const float*)d_in[1];
    const float* sw1 = (const float*)d_in[2];
    const float* sc1 = (const float*)d_in[3];
    const float* bw2 = (const float*)d_in[4];
    const float* sw2 = (const float*)d_in[5];
    const float* sc2 = (const float*)d_in[6];
    float* out = (float*)d_out;

    char* ws = (char*)d_ws;
    __hip_bfloat16* W1 = (__hip_bfloat16*)ws;                   // 4MB
    __hip_bfloat16* W2 = (__hip_bfloat16*)(ws + (4ull << 20));  // 4MB
    __hip_bfloat16* F1 = (__hip_bfloat16*)(ws + (8ull << 20));  // 32MB
    __hip_bfloat16* Hb = (__hip_bfloat16*)(ws + (40ull << 20)); // 16MB (bf16)
    __hip_bfloat16* Pp = (__hip_bfloat16*)(ws + (72ull << 20)); // 32MB (bf16)

    if (ws_size < (104ull << 20)) return;

    // fused: expand_x (8192 blocks) + prep W1 (1024) + prep W2 (1024)
    init_fused<<<10240, 256, 0, stream>>>(x, F1, bw1, sw1, sc1, W1, bw2, sw2, sc2, W2);

    // GEMM1: (8192 x 2048) @ (1024 x 2048)^T + GELU -> Hb (bf16), 512 threads
    kan_gemm1<<<dim3(TOKENS / 128, D_HID / 128), 512, 0, stream>>>(F1, W1, Hb);

    // GEMM2: expand(Hb) @ (256 x 8192)^T -> 8 bf16 partial slices
    kan_gemm2<<<dim3(TOKENS / 128, 1, 8), 512, 0, stream>>>(Hb, W2, Pp);

    // Reduce partials -> out
    const int nvec = TOKENS * D_IN / 4;  // 524288 groups of 4
    reduce_split<<<(nvec + 255) / 256, 256, 0, stream>>>(Pp, out, nvec);
}

// Round 23
// 127.165 us; speedup vs baseline: 1.0135x; 1.0135x over previous
//
#include <hip/hip_runtime.h>
#include <hip/hip_bf16.h>
#include <math.h>

// KAN 2-layer forward, MI355X (gfx950) — FINAL (r18/r21 config, 127.4us best).
//   init_fused   : prep W1, prep W2, expand x -> F1.
//   kan_gemm1    : 512 thr, 128x128, BK=64, dbuf, counted vmcnt(4), setprio,
//                  8 waves (2x4, per-wave 64x32), H bf16 out. 2 blk/CU.
//   kan_gemm2    : 512 thr, BM=128, BN=256, BK=64, split-K=8, 48KB LDS,
//                  plain 2-barrier, fused in-staging feature expansion,
//                  bf16 partial stores (32MB). 2 blk/CU = 16 waves/CU.
//   reduce_split : sum 8 bf16 slices in f32 -> out.
// Final ablation ledger (gemm2 dur us): r6 69 | counted-vmcnt 158 | BK32 87 |
// BN128 98 | reg-only 212 | fused-reduce+fence 229 | XCD-swz 71.5 | r13 67 |
// LDS-B-dbuf(1blk/CU) 98 | r16 65 | splitK16 69 | reg-B-dbuf 93 | 1024thr 79 |
// GLL-first null. gemm1: 256thr 48 | 512thr 45 | 1024thr regress. Frozen.

typedef __attribute__((ext_vector_type(8))) short bf16x8;   // 8 x bf16
typedef __attribute__((ext_vector_type(4))) float f32x4;
typedef __attribute__((ext_vector_type(4))) unsigned short u16x4;

#define TOKENS 8192
#define D_IN   256
#define D_HID  1024

// ---- exact uniform-cubic-B-spline features (closed form) ----
__device__ __forceinline__ void kan_features(float x, float f[8]) {
    f[0] = x * __builtin_amdgcn_rcpf(1.0f + __expf(-x));   // silu via v_rcp
    const float s = (x + 1.0f) * 1.5f + 3.0f;
    const float cf = floorf(s);
    const float u = s - cf;
    const int c = (int)cf;
    const float u2 = u * u, u3 = u2 * u;
    const float k6 = 1.0f / 6.0f;
    const float v3 = u3 * k6;
    const float v2 = (-3.0f * u3 + 3.0f * u2 + 3.0f * u + 1.0f) * k6;
    const float v1 = (3.0f * u3 - 6.0f * u2 + 4.0f) * k6;
    const float w1 = 1.0f - u;
    const float v0 = w1 * w1 * w1 * k6;
    const bool in = (s >= 0.0f) && (s < 9.0f);
#pragma unroll
    for (int j = 0; j < 6; ++j) {
        int d = c - j;
        float bv = (d == 0) ? v3 : (d == 1) ? v2 : (d == 2) ? v1 : (d == 3) ? v0 : 0.0f;
        f[1 + j] = in ? bv : 0.0f;
    }
    f[7] = 0.0f;
}

__device__ __forceinline__ void features_to_bf16(const float f[8], __hip_bfloat16 fb[8]) {
#pragma unroll
    for (int j = 0; j < 8; ++j) fb[j] = __float2bfloat16(f[j]);
}

// ---------------- fused init: expand_x (blocks 0..8191), prep W1, prep W2 ----------
__global__ void init_fused(const float* __restrict__ X, __hip_bfloat16* __restrict__ F,
                           const float* __restrict__ bw1, const float* __restrict__ sw1,
                           const float* __restrict__ sc1, __hip_bfloat16* __restrict__ W1,
                           const float* __restrict__ bw2, const float* __restrict__ sw2,
                           const float* __restrict__ sc2, __hip_bfloat16* __restrict__ W2) {
    const int b = blockIdx.x;
    if (b < 8192) {                          // expand x: 2M elements
        int idx = b * 256 + threadIdx.x;
        float f[8];
        kan_features(X[idx], f);
        __hip_bfloat16 fb[8];
        features_to_bf16(f, fb);
        *(bf16x8*)&F[(size_t)idx * 8] = *(bf16x8*)fb;
        return;
    }
    const bool w1 = (b < 9216);
    int idx = (w1 ? (b - 8192) : (b - 9216)) * 256 + threadIdx.x;   // < 262144
    const float* bw = w1 ? bw1 : bw2;
    const float* sw = w1 ? sw1 : sw2;
    const float* sc = w1 ? sc1 : sc2;
    __hip_bfloat16* Wo = w1 ? W1 : W2;
    float scl = sc[idx];
    __hip_bfloat16 row[8];
    row[0] = __float2bfloat16(bw[idx]);
#pragma unroll
    for (int j = 0; j < 6; ++j)
        row[1 + j] = __float2bfloat16(sw[idx * 6 + j] * scl);
    row[7] = __float2bfloat16(0.0f);
    *(bf16x8*)&Wo[(size_t)idx * 8] = *(bf16x8*)row;
}

#define GLL(src, dst) __builtin_amdgcn_global_load_lds(                         \
    (const __attribute__((address_space(1))) void*)(src),                       \
    (__attribute__((address_space(3))) void*)(dst), 16, 0, 0)

// ---------------- GEMM1: H = bf16(GELU(F1 @ W1^T)), 128x128, BK=64, 512 thr ----
// 8 waves (2x4), per-wave 64x32 output; dbuf + counted vmcnt(4) + setprio.
__global__ __launch_bounds__(512, 2)
void kan_gemm1(const __hip_bfloat16* __restrict__ A,
               const __hip_bfloat16* __restrict__ W,
               __hip_bfloat16* __restrict__ H) {
    constexpr int K = D_IN * 8;            // 2048
    constexpr int NT = K / 64;             // 32 k-tiles
    __shared__ __hip_bfloat16 Al[2][128 * 64];
    __shared__ __hip_bfloat16 Bl[2][128 * 64];

    const int tid = threadIdx.x;
    const int wid = tid >> 6, lane = tid & 63;
    const int wm = wid >> 2, wn = wid & 3;  // 2x4 waves: 64-row x 32-col tiles
    const int lr = lane & 15, lg = lane >> 4;
    const int n0 = blockIdx.x * 128, o0 = blockIdx.y * 128;

    int srow[2], sslot[2];
#pragma unroll
    for (int p = 0; p < 2; ++p) {
        int item = tid + p * 512;
        srow[p] = item >> 3;
        sslot[p] = (item & 7) ^ (srow[p] & 7);
    }
    int aoff[2][4], boff[2][2];
#pragma unroll
    for (int ks = 0; ks < 2; ++ks) {
#pragma unroll
        for (int f = 0; f < 4; ++f) {
            int ar = wm * 64 + f * 16 + lr;
            aoff[ks][f] = ar * 64 + (((ks * 4 + lg) ^ (ar & 7)) * 8);
        }
#pragma unroll
        for (int f = 0; f < 2; ++f) {
            int br = wn * 32 + f * 16 + lr;
            boff[ks][f] = br * 64 + (((ks * 4 + lg) ^ (br & 7)) * 8);
        }
    }

    f32x4 acc[4][2] = {};

#define STG1(buf, kt)                                                           \
    do {                                                                        \
        _Pragma("unroll")                                                       \
        for (int p = 0; p < 2; ++p) {                                           \
            GLL(A + (size_t)(n0 + srow[p]) * K + (kt) * 64 + sslot[p] * 8,      \
                &Al[buf][(tid + p * 512) * 8]);                                 \
            GLL(W + (size_t)(o0 + srow[p]) * K + (kt) * 64 + sslot[p] * 8,      \
                &Bl[buf][(tid + p * 512) * 8]);                                 \
        }                                                                       \
    } while (0)

    STG1(0, 0);
    STG1(1, 1);
    for (int t = 0; t < NT; ++t) {
        const int cur = t & 1;
        asm volatile("s_waitcnt vmcnt(4)" ::: "memory");
        __builtin_amdgcn_s_barrier();
        __builtin_amdgcn_sched_barrier(0);
        __builtin_amdgcn_s_setprio(1);
#pragma unroll
        for (int ks = 0; ks < 2; ++ks) {
            bf16x8 af[4], bfr[2];
#pragma unroll
            for (int f = 0; f < 4; ++f) af[f] = *(const bf16x8*)&Al[cur][aoff[ks][f]];
#pragma unroll
            for (int f = 0; f < 2; ++f) bfr[f] = *(const bf16x8*)&Bl[cur][boff[ks][f]];
#pragma unroll
            for (int fm = 0; fm < 4; ++fm)
#pragma unroll
                for (int fn = 0; fn < 2; ++fn)
                    acc[fm][fn] = __builtin_amdgcn_mfma_f32_16x16x32_bf16(
                        af[fm], bfr[fn], acc[fm][fn], 0, 0, 0);
        }
        __builtin_amdgcn_s_setprio(0);
        asm volatile("s_waitcnt lgkmcnt(0)" ::: "memory");
        __builtin_amdgcn_s_barrier();
        __builtin_amdgcn_sched_barrier(0);
        const int kn = (t + 2 < NT) ? t + 2 : NT - 1;
        STG1(cur, kn);
    }
#undef STG1
#pragma unroll
    for (int fm = 0; fm < 4; ++fm) {
#pragma unroll
        for (int fn = 0; fn < 2; ++fn) {
            int col = o0 + wn * 32 + fn * 16 + lr;
#pragma unroll
            for (int r = 0; r < 4; ++r) {
                int row = n0 + wm * 64 + fm * 16 + lg * 4 + r;
                float v = acc[fm][fn][r];
                float g = 0.5f * v * (1.0f + erff(v * 0.70710678118f));
                H[(size_t)row * D_HID + col] = __float2bfloat16(g);
            }
        }
    }
}

// ---------------- GEMM2: BM=128, 512thr, BN=256, BK=64, split-K=8 ----------------
__global__ __launch_bounds__(512, 2)
void kan_gemm2(const __hip_bfloat16* __restrict__ H,
               const __hip_bfloat16* __restrict__ W,
               __hip_bfloat16* __restrict__ P) {
    constexpr int OUT = D_IN, KD = D_HID * 8;   // 8192
    constexpr int NTT = KD / 64;                // 128 k-tiles
    __shared__ __hip_bfloat16 Al[128 * 64];     // 16KB
    __shared__ __hip_bfloat16 Bl[256 * 64];     // 32KB (reused as f32 in epi)

    const int tid = threadIdx.x;
    const int wid = tid >> 6, lane = tid & 63;
    const int wm = wid >> 2, wn = wid & 3;      // 2x4 waves: 64-row x 64-col tiles
    const int lr = lane & 15, lg = lane >> 4;
    const int n0 = blockIdx.x * 128;

    const int per = NTT / 8;                    // 16
    const int ks0 = blockIdx.z * per, ks1 = ks0 + per;

    int srow[4], sslot[4];
#pragma unroll
    for (int p = 0; p < 4; ++p) {
        int item = tid + p * 512;
        srow[p] = item >> 3;
        sslot[p] = (item & 7) ^ (srow[p] & 7);
    }
    const int ar0 = tid >> 3, ac = tid & 7;
    const __hip_bfloat16* hp0 = H + (size_t)(n0 + ar0) * D_HID + ac;
    const __hip_bfloat16* hp1 = H + (size_t)(n0 + ar0 + 64) * D_HID + ac;
    const int aw0 = ar0 * 64 + ((ac ^ (ar0 & 7)) * 8);
    const int aw1 = (ar0 + 64) * 64 + ((ac ^ (ar0 & 7)) * 8);

    int aoff[2][4], boff[2][4];
#pragma unroll
    for (int ks = 0; ks < 2; ++ks)
#pragma unroll
        for (int f = 0; f < 4; ++f) {
            int ar = wm * 64 + f * 16 + lr;
            int br = wn * 64 + f * 16 + lr;
            aoff[ks][f] = ar * 64 + (((ks * 4 + lg) ^ (ar & 7)) * 8);
            boff[ks][f] = br * 64 + (((ks * 4 + lg) ^ (br & 7)) * 8);
        }

    f32x4 acc[4][4] = {};

    float hv0 = __bfloat162float(hp0[(size_t)ks0 * 8]);
    float hv1 = __bfloat162float(hp1[(size_t)ks0 * 8]);

    for (int kt = ks0; kt < ks1; ++kt) {
        float hc0 = hv0, hc1 = hv1;
        const int knext = (kt + 1 < ks1) ? kt + 1 : ks1 - 1;
        hv0 = __bfloat162float(hp0[(size_t)knext * 8]);
        hv1 = __bfloat162float(hp1[(size_t)knext * 8]);
        {   // features -> swizzled LDS
            float ff[8]; __hip_bfloat16 fb[8];
            kan_features(hc0, ff); features_to_bf16(ff, fb);
            *(bf16x8*)&Al[aw0] = *(bf16x8*)fb;
            kan_features(hc1, ff); features_to_bf16(ff, fb);
            *(bf16x8*)&Al[aw1] = *(bf16x8*)fb;
        }
#pragma unroll
        for (int p = 0; p < 4; ++p)
            GLL(W + (size_t)srow[p] * KD + (size_t)kt * 64 + sslot[p] * 8,
                &Bl[(tid + p * 512) * 8]);
        __syncthreads();
#pragma unroll
        for (int ks = 0; ks < 2; ++ks) {
            bf16x8 af[4], bfr[4];
#pragma unroll
            for (int f = 0; f < 4; ++f) af[f] = *(const bf16x8*)&Al[aoff[ks][f]];
#pragma unroll
            for (int f = 0; f < 4; ++f) bfr[f] = *(const bf16x8*)&Bl[boff[ks][f]];
#pragma unroll
            for (int fm = 0; fm < 4; ++fm)
#pragma unroll
                for (int fn = 0; fn < 4; ++fn)
                    acc[fm][fn] = __builtin_amdgcn_mfma_f32_16x16x32_bf16(
                        af[fm], bfr[fn], acc[fm][fn], 0, 0, 0);
        }
        __syncthreads();
    }

    // ---- epilogue: 4 quarter-passes (32 rows x 256 cols f32 in Bl), bf16 stores ----
    float* Pl = (float*)Bl;
    const size_t zoff = (size_t)blockIdx.z * TOKENS * OUT;
#pragma unroll
    for (int q = 0; q < 4; ++q) {
        __syncthreads();
        if (wm == (q >> 1)) {
#pragma unroll
            for (int fp = 0; fp < 2; ++fp) {     // fm = (q&1)*2 + fp
                int fm = (q & 1) * 2 + fp;
#pragma unroll
                for (int fn = 0; fn < 4; ++fn) {
                    int c = wn * 64 + fn * 16 + lr;
#pragma unroll
                    for (int r = 0; r < 4; ++r)
                        Pl[(fp * 16 + lg * 4 + r) * 256 + c] = acc[fm][fn][r];
                }
            }
        }
        __syncthreads();
#pragma unroll
        for (int p = 0; p < 4; ++p) {
            int v = tid + p * 512;               // 0..2047
            int row = v >> 6, cv = (v & 63) * 4;
            const float* src = &Pl[row * 256 + cv];
            __hip_bfloat16 ob[4];
#pragma unroll
            for (int j = 0; j < 4; ++j) ob[j] = __float2bfloat16(src[j]);
            *(u16x4*)&P[zoff + (size_t)(n0 + q * 32 + row) * OUT + cv] =
                *(const u16x4*)ob;
        }
    }
}

// ---------------- reduce 8 bf16 partial slices -> f32 out ----------------
__global__ void reduce_split(const __hip_bfloat16* __restrict__ P,
                             float* __restrict__ out, int nvec) {
    int i = blockIdx.x * 256 + threadIdx.x;
    if (i >= nvec) return;                       // i indexes groups of 4 elems
    float s[4] = {0.f, 0.f, 0.f, 0.f};
#pragma unroll
    for (int z = 0; z < 8; ++z) {
        u16x4 v = *(const u16x4*)&P[(size_t)z * TOKENS * D_IN + (size_t)i * 4];
#pragma unroll
        for (int j = 0; j < 4; ++j) {
            unsigned int bits = ((unsigned int)(unsigned short)v[j]) << 16;
            s[j] += __uint_as_float(bits);       // exact bf16 -> f32
        }
    }
    f32x4 o = {s[0], s[1], s[2], s[3]};
    *(f32x4*)&out[(size_t)i * 4] = o;
}

extern "C" void kernel_launch(void* const* d_in, const int* in_sizes, int n_in,
                              void* d_out, int out_size, void* d_ws, size_t ws_size,
                              hipStream_t stream) {
    const float* x   = (const float*)d_in[0];
    const float* bw1 = (const float*)d_in[1];
    const float* sw1 = (const float*)d_in[2];
    const float* sc1 = (const float*)d_in[3];
    const float* bw2 = (const float*)d_in[4];
    const float* sw2 = (const float*)d_in[5];
    const float* sc2 = (const float*)d_in[6];
    float* out = (float*)d_out;

    char* ws = (char*)d_ws;
    __hip_bfloat16* W1 = (__hip_bfloat16*)ws;                   // 4MB
    __hip_bfloat16* W2 = (__hip_bfloat16*)(ws + (4ull << 20));  // 4MB
    __hip_bfloat16* F1 = (__hip_bfloat16*)(ws + (8ull << 20));  // 32MB
    __hip_bfloat16* Hb = (__hip_bfloat16*)(ws + (40ull << 20)); // 16MB (bf16)
    __hip_bfloat16* Pp = (__hip_bfloat16*)(ws + (72ull << 20)); // 32MB (bf16)

    if (ws_size < (104ull << 20)) return;

    // fused: expand_x (8192 blocks) + prep W1 (1024) + prep W2 (1024)
    init_fused<<<10240, 256, 0, stream>>>(x, F1, bw1, sw1, sc1, W1, bw2, sw2, sc2, W2);

    // GEMM1: (8192 x 2048) @ (1024 x 2048)^T + GELU -> Hb (bf16), 512 threads
    kan_gemm1<<<dim3(TOKENS / 128, D_HID / 128), 512, 0, stream>>>(F1, W1, Hb);

    // GEMM2: expand(Hb) @ (256 x 8192)^T -> 8 bf16 partial slices
    kan_gemm2<<<dim3(TOKENS / 128, 1, 8), 512, 0, stream>>>(Hb, W2, Pp);

    // Reduce partials -> out
    const int nvec = TOKENS * D_IN / 4;  // 524288 groups of 4
    reduce_split<<<(nvec + 255) / 256, 256, 0, stream>>>(Pp, out, nvec);
}